// Round 3
// baseline (739.010 us; speedup 1.0000x reference)
//
#include <hip/hip_runtime.h>

// ---------------------------------------------------------------------------
// TiedMultiheadAttention  (B=1, N=64, L=512, D=768, H=12, DK=64)
//
// R3: fp32-source projections get BN=96 (grid 2048 = clean residency rounds),
//     register-prefetch software pipeline, hw bf16 converts. bf16 GEMMs keep
//     the m97 global_load_lds structure.
// ---------------------------------------------------------------------------

typedef __bf16 bf16x8 __attribute__((ext_vector_type(8)));
typedef float f32x4 __attribute__((ext_vector_type(4)));

__device__ __forceinline__ unsigned short f2bf(float f) {
  __bf16 h = (__bf16)f;  // RNE; gfx950 lowers to v_cvt_pk_bf16_f32
  return __builtin_bit_cast(unsigned short, h);
}

__device__ __forceinline__ void gll16(const unsigned short* g, unsigned short* l) {
  __builtin_amdgcn_global_load_lds(
      (const __attribute__((address_space(1))) unsigned int*)g,
      (__attribute__((address_space(3))) unsigned int*)l, 16, 0, 0);
}

enum { MODE_QCAT = 0, MODE_VT = 1, MODE_ATT = 2, MODE_OUTWS = 3, MODE_OUT_BIAS = 4 };

constexpr int BM = 128, BK = 32;

// C = A @ B^T. A:[M,K] lda, B:[N,K] ldb. Batch via blockIdx.z (opt split-K).
// F32S: fp32 A/B, VGPR-convert staging with register prefetch (BNT=96 or 128).
// else: bf16 A/B via global_load_lds, m97 layout (BNT must be 128).
// SWZ : XCD-aware swizzle (1-D grid), ntiles_m % 8 == 0.
template <int MODE, bool F32S, bool SWZ, int KS, int BNT>
__global__ __launch_bounds__(256, 2) void gemm_bt(
    const void* __restrict__ Av, const void* __restrict__ Bv,
    const float* __restrict__ bias, void* __restrict__ Cv,
    int K, int lda, int ldb, long long a_bs, long long b_bs,
    float alpha, int ntn) {
  constexpr int LP = F32S ? 40 : 32;   // LDS row stride (bf16 elems)
  constexpr int WN = BNT / 2;          // cols per wave (2 waves in n)
  constexpr int NU = WN / 16;          // 16-wide col tiles per wave

  __shared__ unsigned short As[BM * LP];
  __shared__ unsigned short Bs[BNT * LP];

  const int tid = threadIdx.x;
  const int wave = tid >> 6;
  const int lane = tid & 63;
  const int wm = wave >> 1, wn = wave & 1;

  int tm, tn;
  if constexpr (SWZ) {
    const int bid = blockIdx.x;
    const int xcd = bid & 7;
    const int k = bid >> 3;
    tn = k % ntn;
    tm = (k / ntn) * 8 + xcd;
  } else {
    tn = blockIdx.x;
    tm = blockIdx.y;
  }
  int batch = blockIdx.z, ks = 0;
  if constexpr (KS > 1) { ks = batch % KS; batch /= KS; }

  const long long m0 = (long long)tm * BM;
  const long long n0 = (long long)tn * BNT;

  f32x4 acc[4][NU] = {};
  const int l15 = lane & 15;
  const int kq = (lane >> 4) * 8;

  // MFMA segment (shared by both staging paths)
  auto mfma_step = [&]() {
    bf16x8 af[4], bfr[NU];
#pragma unroll
    for (int t = 0; t < 4; ++t)
      af[t] = *(const bf16x8*)&As[(wm * 64 + t * 16 + l15) * LP + kq];
#pragma unroll
    for (int u = 0; u < NU; ++u)
      bfr[u] = *(const bf16x8*)&Bs[(wn * WN + u * 16 + l15) * LP + kq];
#pragma unroll
    for (int t = 0; t < 4; ++t)
#pragma unroll
      for (int u = 0; u < NU; ++u)
        acc[t][u] = __builtin_amdgcn_mfma_f32_16x16x32_bf16(af[t], bfr[u], acc[t][u], 0, 0, 0);
  };

  if constexpr (F32S) {
    const float* Ab = (const float*)Av + (long long)batch * a_bs + (long long)ks * K;
    const float* Bb = (const float*)Bv + (long long)batch * b_bs + (long long)ks * K;
    const int row = tid >> 3;        // 0..31
    const int c4 = (tid & 7) * 4;    // 0,4,..,28
    constexpr int BRR = BNT / 32;    // B row groups (3 or 4)

    float4 pa[4], pb[BRR];
    auto issue = [&](int k0) {
#pragma unroll
      for (int rr = 0; rr < 4; ++rr)
        pa[rr] = *(const float4*)(Ab + (m0 + row + rr * 32) * (long long)lda + k0 + c4);
#pragma unroll
      for (int rr = 0; rr < BRR; ++rr)
        pb[rr] = *(const float4*)(Bb + (n0 + row + rr * 32) * (long long)ldb + k0 + c4);
    };

    issue(0);
    for (int k0 = 0; k0 < K; k0 += BK) {
#pragma unroll
      for (int rr = 0; rr < 4; ++rr) {
        ushort4 ap{f2bf(pa[rr].x), f2bf(pa[rr].y), f2bf(pa[rr].z), f2bf(pa[rr].w)};
        *(ushort4*)&As[(row + rr * 32) * LP + c4] = ap;
      }
#pragma unroll
      for (int rr = 0; rr < BRR; ++rr) {
        ushort4 bp{f2bf(pb[rr].x), f2bf(pb[rr].y), f2bf(pb[rr].z), f2bf(pb[rr].w)};
        *(ushort4*)&Bs[(row + rr * 32) * LP + c4] = bp;
      }
      __syncthreads();
      if (k0 + BK < K) issue(k0 + BK);  // prefetch next tile; latency hides behind MFMA
      mfma_step();
      __syncthreads();
    }
  } else {
    static_assert(F32S || BNT == 128, "gll path assumes 128-wide tile");
    const unsigned short* Ab = (const unsigned short*)Av + (long long)batch * a_bs + (long long)ks * K;
    const unsigned short* Bb = (const unsigned short*)Bv + (long long)batch * b_bs + (long long)ks * K;
    const int r_in = lane >> 2;      // 0..15
    const int c8 = (lane & 3) * 8;   // 0,8,16,24

    for (int k0 = 0; k0 < K; k0 += BK) {
#pragma unroll
      for (int t = 0; t < 2; ++t) {
        const int rb = t * 64 + wave * 16;  // wave-uniform row base
        gll16(Ab + (m0 + rb + r_in) * (long long)lda + k0 + c8, &As[rb * LP]);
        gll16(Bb + (n0 + rb + r_in) * (long long)ldb + k0 + c8, &Bs[rb * LP]);
      }
      __syncthreads();
      mfma_step();
      __syncthreads();
    }
  }

  // Epilogue: D[m][n] with m_rel=(lane>>4)*4+r, n_rel=lane&15 per 16x16 tile
#pragma unroll
  for (int t = 0; t < 4; ++t) {
#pragma unroll
    for (int u = 0; u < NU; ++u) {
      const long long col = n0 + wn * WN + u * 16 + l15;
#pragma unroll
      for (int r = 0; r < 4; ++r) {
        const long long row = m0 + wm * 64 + t * 16 + (lane >> 4) * 4 + r;
        float v = acc[t][u][r];
        if constexpr (MODE == MODE_QCAT) {
          v = (v + bias[col]) * alpha;
          const long long h = col >> 6, kk = col & 63, n = row >> 9, i = row & 511;
          ((unsigned short*)Cv)[((h * 512 + i) << 12) + (n << 6) + kk] = f2bf(v);
        } else if constexpr (MODE == MODE_VT) {
          v = v + bias[col];
          const long long h = col >> 6, kk = col & 63, n = row >> 9, j = row & 511;
          ((unsigned short*)Cv)[(((h << 12) + (n << 6) + kk) << 9) + j] = f2bf(v);
        } else if constexpr (MODE == MODE_ATT) {
          float* p = &((float*)Cv)[((long long)batch << 18) + (row << 9) + col];
          if constexpr (KS > 1) atomicAdd(p, v); else *p = v;
        } else if constexpr (MODE == MODE_OUTWS) {
          const long long n = col >> 6, kk = col & 63;
          ((unsigned short*)Cv)[(n * 512 + row) * 768 + (long long)batch * 64 + kk] = f2bf(v);
        } else {  // MODE_OUT_BIAS
          ((float*)Cv)[row * 768 + col] = v + bias[col];
        }
      }
    }
  }
}

// softmax over last dim: att fp32 [12][512][512] -> bf16
__global__ __launch_bounds__(256) void softmax_rows(const float* __restrict__ att,
                                                    unsigned short* __restrict__ outb) {
  const long long rowbase = (long long)blockIdx.x << 9;
  const int tid = threadIdx.x;
  float a = att[rowbase + tid];
  float b = att[rowbase + tid + 256];

  float m = fmaxf(a, b);
#pragma unroll
  for (int off = 32; off; off >>= 1) m = fmaxf(m, __shfl_down(m, off));
  __shared__ float redm[4];
  if ((tid & 63) == 0) redm[tid >> 6] = m;
  __syncthreads();
  m = fmaxf(fmaxf(redm[0], redm[1]), fmaxf(redm[2], redm[3]));

  const float e0 = __expf(a - m), e1 = __expf(b - m);
  float s = e0 + e1;
#pragma unroll
  for (int off = 32; off; off >>= 1) s += __shfl_down(s, off);
  __shared__ float reds[4];
  if ((tid & 63) == 0) reds[tid >> 6] = s;
  __syncthreads();
  s = reds[0] + reds[1] + reds[2] + reds[3];

  const float inv = 1.0f / s;
  outb[rowbase + tid] = f2bf(e0 * inv);
  outb[rowbase + tid + 256] = f2bf(e1 * inv);
}

// fp32 -> bf16, 8 elems/thread (n must be multiple of 2048)
__global__ __launch_bounds__(256) void cvt_bf16(const float* __restrict__ in,
                                                unsigned short* __restrict__ out) {
  const long long i = ((long long)blockIdx.x * 256 + threadIdx.x) * 8;
  const float4 a = *(const float4*)(in + i);
  const float4 b = *(const float4*)(in + i + 4);
  uint4 p;
  p.x = (unsigned)f2bf(a.x) | ((unsigned)f2bf(a.y) << 16);
  p.y = (unsigned)f2bf(a.z) | ((unsigned)f2bf(a.w) << 16);
  p.z = (unsigned)f2bf(b.x) | ((unsigned)f2bf(b.y) << 16);
  p.w = (unsigned)f2bf(b.z) | ((unsigned)f2bf(b.w) << 16);
  *(uint4*)(out + i) = p;
}

extern "C" void kernel_launch(void* const* d_in, const int* in_sizes, int n_in,
                              void* d_out, int out_size, void* d_ws, size_t ws_size,
                              hipStream_t stream) {
  const float* query = (const float*)d_in[0];
  const float* key   = (const float*)d_in[1];
  const float* value = (const float*)d_in[2];
  const float* Wq = (const float*)d_in[3];
  const float* bq = (const float*)d_in[4];
  const float* Wk = (const float*)d_in[5];
  const float* bk = (const float*)d_in[6];
  const float* Wv = (const float*)d_in[7];
  const float* bv = (const float*)d_in[8];
  const float* Wo = (const float*)d_in[9];
  const float* bo = (const float*)d_in[10];
  float* out = (float*)d_out;

  char* ws = (char*)d_ws;
  unsigned short* q_ws  = (unsigned short*)(ws);               // 50,331,648 B
  unsigned short* k_ws  = (unsigned short*)(ws + 50331648);    // 50,331,648 B
  unsigned short* vt_ws = (unsigned short*)(ws + 100663296);   // 50,331,648 B
  float*          att   = (float*)(ws + 150994944);            // 12,582,912 B
  unsigned short* wo_b  = (unsigned short*)(ws + 163577856);   //  1,179,648 B
  unsigned short* att_b = k_ws;   // k_ws dead after s2
  unsigned short* out_ws = q_ws;  // q_ws dead after s2

  const dim3 blk(256);

  // Wo fp32 -> bf16 (589824 elems = 288 * 2048)
  cvt_bf16<<<288, blk, 0, stream>>>(Wo, wo_b);

  // s1: projections, BN=96 -> grid 2048 (= 2 x 1024 residency), ntm=256, ntn=8
  gemm_bt<MODE_QCAT, true, true, 1, 96><<<dim3(2048, 1, 1), blk, 0, stream>>>(
      query, Wq, bq, q_ws, 768, 768, 768, 0, 0, 0.015625f, 8);
  gemm_bt<MODE_QCAT, true, true, 1, 96><<<dim3(2048, 1, 1), blk, 0, stream>>>(
      key, Wk, bk, k_ws, 768, 768, 768, 0, 0, 1.0f, 8);
  gemm_bt<MODE_VT, true, true, 1, 96><<<dim3(2048, 1, 1), blk, 0, stream>>>(
      value, Wv, bv, vt_ws, 768, 768, 768, 0, 0, 1.0f, 8);

  // s2: tied scores, per-head [512 x 4096] @ [512 x 4096]^T, split-K x4
  hipMemsetAsync(att, 0, 12582912, stream);
  gemm_bt<MODE_ATT, false, false, 4, 128><<<dim3(4, 4, 48), blk, 0, stream>>>(
      q_ws, k_ws, nullptr, att, 1024, 4096, 4096, 2097152LL, 2097152LL, 1.0f, 4);

  // s3: softmax
  softmax_rows<<<6144, blk, 0, stream>>>(att, att_b);

  // s4: per-head att @ Vt^T -> out_ws [(n*512+i)][h*64+k]
  gemm_bt<MODE_OUTWS, false, false, 1, 128><<<dim3(32, 4, 12), blk, 0, stream>>>(
      att_b, vt_ws, nullptr, out_ws, 512, 512, 512, 262144LL, 2097152LL, 1.0f, 32);

  // s5: output projection -> fp32 d_out, XCD swizzle
  gemm_bt<MODE_OUT_BIAS, false, true, 1, 128><<<dim3(1536, 1, 1), blk, 0, stream>>>(
      out_ws, wo_b, bo, out, 768, 768, 768, 0, 0, 1.0f, 6);
}